// Round 6
// baseline (4107.965 us; speedup 1.0000x reference)
//
#include <hip/hip_runtime.h>
#include <math.h>

#define Bc 4
#define Nc 8192
#define NPOINTc 2048
#define NSAMPLEc 16
#define CINc 64
#define COUTc 128
#define FDIMc 67
#define NBUCK 128
#define EPSc 1e-5f

// ---------------------------------------------------------------- K0: |xyz|^2 (f32, rn-chain)
// Mirrors np/torch sum(x**2, -1): squares rounded individually, sequential adds, no FMA.
__global__ void sq_norm_kernel(const float* __restrict__ xyz, float* __restrict__ sn) {
    int i = blockIdx.x * blockDim.x + threadIdx.x;
    if (i < Bc * Nc) {
        float x = xyz[i * 3], y = xyz[i * 3 + 1], z = xyz[i * 3 + 2];
        sn[i] = __fadd_rn(__fadd_rn(__fmul_rn(x, x), __fmul_rn(y, y)), __fmul_rn(z, z));
    }
}

// ---------------------------------------------------------------- K1: FPS (f32 rn-chain)
// One block/batch, 512 threads, 16 pts/thread. Coords staged in LDS so winner
// coords are read directly. Tie -> lowest index (argmax first-max).
// Distance: ((dx*dx + dy*dy) + dz*dz), each op rounded, NO FMA.
__global__ __launch_bounds__(512) void fps_kernel(const float* __restrict__ xyz,
                                                  int* __restrict__ cent,
                                                  float* __restrict__ newxyz) {
    const int b = blockIdx.x;
    const float* base = xyz + (size_t)b * Nc * 3;
    const int t = threadIdx.x;
    const int lane = t & 63, wid = t >> 6;   // 8 waves

    __shared__ float  P[Nc * 3];             // 96 KB
    __shared__ float  wd[8];
    __shared__ int    wi[8];
    __shared__ int    winS;

    for (int e = t; e < Nc * 3; e += 512) P[e] = base[e];

    float X[16], Y[16], Z[16], D[16];
#pragma unroll
    for (int k = 0; k < 16; ++k) {
        const int n = t + (k << 9);
        X[k] = base[n * 3 + 0];
        Y[k] = base[n * 3 + 1];
        Z[k] = base[n * 3 + 2];
        D[k] = 1e10f;
    }
    if (t == 0) {
        winS = 0;
        cent[b * NPOINTc] = 0;
        float* o = newxyz + (size_t)b * NPOINTc * 3;
        o[0] = base[0]; o[1] = base[1]; o[2] = base[2];
    }
    __syncthreads();

    for (int it = 1; it < NPOINTc; ++it) {
        const int w = winS;
        const float cx = P[w * 3 + 0];       // broadcast reads, conflict-free
        const float cy = P[w * 3 + 1];
        const float cz = P[w * 3 + 2];

        float bd = -1.0f; int bi = 0;
#pragma unroll
        for (int k = 0; k < 16; ++k) {
            const float dx = __fsub_rn(X[k], cx);
            const float dy = __fsub_rn(Y[k], cy);
            const float dz = __fsub_rn(Z[k], cz);
            const float d2 = __fadd_rn(__fadd_rn(__fmul_rn(dx, dx), __fmul_rn(dy, dy)),
                                       __fmul_rn(dz, dz));
            if (d2 < D[k]) D[k] = d2;        // minimum(distance, dist)
            // n = t + k*512 ascends with k: strict > keeps lowest index on tie
            if (D[k] > bd) { bd = D[k]; bi = t + (k << 9); }
        }
        // intra-wave butterfly lex-argmax (tie -> lowest global index)
#pragma unroll
        for (int off = 32; off > 0; off >>= 1) {
            const float od = __shfl_xor(bd, off, 64);
            const int   oi = __shfl_xor(bi, off, 64);
            if (od > bd || (od == bd && oi < bi)) { bd = od; bi = oi; }
        }
        if (lane == 0) { wd[wid] = bd; wi[wid] = bi; }
        __syncthreads();                     // A: partials visible

        if (t == 0) {
            float rd = wd[0]; int ri = wi[0];
#pragma unroll
            for (int j = 1; j < 8; ++j) {
                if (wd[j] > rd || (wd[j] == rd && wi[j] < ri)) { rd = wd[j]; ri = wi[j]; }
            }
            winS = ri;
            cent[b * NPOINTc + it] = ri;
            float* o = newxyz + ((size_t)b * NPOINTc + it) * 3;
            o[0] = P[ri * 3 + 0]; o[1] = P[ri * 3 + 1]; o[2] = P[ri * 3 + 2];
        }
        __syncthreads();                     // B: winS visible
    }
}

// ---------------------------------------------------------------- K2: KNN (square_distance form)
// One block (256 thr) per (b,m). Torch/PointNet++ square_distance semantics:
//   dist = -2 * matmul(new_xyz, xyz^T);  dist += s1;  dist += s2
// i.e. association ((-2*dot) + s1) + s2, with matmul = BLAS FMA accumulation
// k-ascending: dot = fma(z,mz, fma(y,my, rn(x*mx))). -2*dot is exact (pow2).
// Then clamp at 0 (selection-neutral). 16 masked lex-argmin passes == top_k.
__global__ __launch_bounds__(256) void knn_kernel(const float* __restrict__ xyz,
                                                  const float* __restrict__ sn,
                                                  const int* __restrict__ cent,
                                                  int* __restrict__ knn) {
    const int g = blockIdx.x;                // b*NPOINT + m
    const int b = g >> 11;
    const int t = threadIdx.x;
    const float* base = xyz + (size_t)b * Nc * 3;
    const float* snb = sn + (size_t)b * Nc;

    __shared__ float dist[Nc];               // 32 KB
    __shared__ float rd[256];
    __shared__ int   ri[256];

    const int cm = cent[g];
    const float mx = base[cm * 3 + 0];
    const float my = base[cm * 3 + 1];
    const float mz = base[cm * 3 + 2];
    const float s1 = snb[cm];

    for (int n = t; n < Nc; n += 256) {
        const float x = base[n * 3 + 0];
        const float y = base[n * 3 + 1];
        const float z = base[n * 3 + 2];
        // BLAS FMA chain, k ascending (x,y,z):
        const float dot = fmaf(z, mz, fmaf(y, my, __fmul_rn(x, mx)));
        // square_distance association: ((-2*dot) + s1) + s2
        float d = __fadd_rn(__fadd_rn(__fmul_rn(-2.0f, dot), s1), snb[n]);
        dist[n] = fmaxf(d, 0.0f);
    }
    __syncthreads();

    int* out = knn + (size_t)g * NSAMPLEc;
    for (int r = 0; r < NSAMPLEc; ++r) {
        float bd = INFINITY; int bi = 0x7fffffff;
        for (int n = t; n < Nc; n += 256) {
            const float d = dist[n];
            if (d < bd) { bd = d; bi = n; }  // n ascending per thread: strict < keeps lowest
        }
        rd[t] = bd; ri[t] = bi;
        __syncthreads();
        for (int s = 128; s > 0; s >>= 1) {
            if (t < s) {
                if (rd[t + s] < rd[t] || (rd[t + s] == rd[t] && ri[t + s] < ri[t])) {
                    rd[t] = rd[t + s]; ri[t] = ri[t + s];
                }
            }
            __syncthreads();
        }
        const int win = ri[0];
        if (t == 0) { out[r] = win; dist[win] = INFINITY; }
        __syncthreads();
    }
}

// ---------------------------------------------------------------- K3: GEMM + BN stats
__global__ __launch_bounds__(128) void gemm_stats_kernel(
        const float* __restrict__ px, const float* __restrict__ xyz,
        const float* __restrict__ newxyz, const int* __restrict__ knn,
        const float* __restrict__ W, const float* __restrict__ bias,
        float* __restrict__ bsum, float* __restrict__ bsq) {
    const int g = blockIdx.x;
    const int b = g >> 11;
    const int t = threadIdx.x;               // channel

    __shared__ float feat[16][FDIMc + 1];
    __shared__ int nidx[16];
    __shared__ float ctr[3];
    if (t < 16) nidx[t] = knn[(size_t)g * NSAMPLEc + t];
    if (t < 3)  ctr[t] = newxyz[(size_t)g * 3 + t];
    __syncthreads();

    for (int e = t; e < 16 * FDIMc; e += 128) {
        const int s = e / FDIMc, i = e % FDIMc;
        float v;
        if (i < CINc) v = px[((size_t)b * Nc + nidx[s]) * CINc + i];
        else          v = __fsub_rn(xyz[((size_t)b * Nc + nidx[s]) * 3 + (i - CINc)], ctr[i - CINc]);
        feat[s][i] = v;
    }
    __syncthreads();

    const float bc = bias[t];
    float s = 0.f, q = 0.f;
    for (int r = 0; r < 16; ++r) {
        float acc = bc;
        for (int i = 0; i < FDIMc; ++i) acc = fmaf(feat[r][i], W[i * COUTc + t], acc);
        s += acc; q += acc * acc;
    }
    atomicAdd(&bsum[(g & (NBUCK - 1)) * COUTc + t], s);
    atomicAdd(&bsq [(g & (NBUCK - 1)) * COUTc + t], q);
}

// ---------------------------------------------------------------- K4: finalize stats
__global__ void stats_finalize_kernel(const float* __restrict__ bsum,
                                      const float* __restrict__ bsq,
                                      const float* __restrict__ gamma,
                                      const float* __restrict__ beta,
                                      float* __restrict__ scsh) {
    const int c = threadIdx.x;  // 128
    float S = 0.f, Q = 0.f;
    for (int k = 0; k < NBUCK; ++k) { S += bsum[k * COUTc + c]; Q += bsq[k * COUTc + c]; }
    const float cnt = (float)(Bc * NPOINTc * NSAMPLEc);
    const float mu = S / cnt;
    const float var = Q / cnt - mu * mu;
    const float sc = gamma[c] / sqrtf(var + EPSc);
    scsh[c] = sc;
    scsh[COUTc + c] = beta[c] - mu * sc;
}

// ---------------------------------------------------------------- K5: GEMM + BN + ReLU + maxpool
__global__ __launch_bounds__(128) void gemm_out_kernel(
        const float* __restrict__ px, const float* __restrict__ xyz,
        const float* __restrict__ newxyz, const int* __restrict__ knn,
        const float* __restrict__ W, const float* __restrict__ bias,
        const float* __restrict__ scsh, float* __restrict__ out) {
    const int g = blockIdx.x;
    const int b = g >> 11;
    const int t = threadIdx.x;               // channel

    __shared__ float feat[16][FDIMc + 1];
    __shared__ int nidx[16];
    __shared__ float ctr[3];
    if (t < 16) nidx[t] = knn[(size_t)g * NSAMPLEc + t];
    if (t < 3)  ctr[t] = newxyz[(size_t)g * 3 + t];
    __syncthreads();

    for (int e = t; e < 16 * FDIMc; e += 128) {
        const int s = e / FDIMc, i = e % FDIMc;
        float v;
        if (i < CINc) v = px[((size_t)b * Nc + nidx[s]) * CINc + i];
        else          v = __fsub_rn(xyz[((size_t)b * Nc + nidx[s]) * 3 + (i - CINc)], ctr[i - CINc]);
        feat[s][i] = v;
    }
    __syncthreads();

    const float bc = bias[t];
    const float sc = scsh[t], sh = scsh[COUTc + t];
    float m = -INFINITY;
    for (int r = 0; r < 16; ++r) {
        float acc = bc;
        for (int i = 0; i < FDIMc; ++i) acc = fmaf(feat[r][i], W[i * COUTc + t], acc);
        const float v = fmaxf(fmaf(acc, sc, sh), 0.0f);   // BN + ReLU
        m = fmaxf(m, v);
    }
    out[(size_t)g * COUTc + t] = m;
}

// ---------------------------------------------------------------- launch
extern "C" void kernel_launch(void* const* d_in, const int* in_sizes, int n_in,
                              void* d_out, int out_size, void* d_ws, size_t ws_size,
                              hipStream_t stream) {
    const float* px    = (const float*)d_in[0];
    const float* xyz   = (const float*)d_in[1];
    const float* W     = (const float*)d_in[2];
    const float* bias  = (const float*)d_in[3];
    const float* gamma = (const float*)d_in[4];
    const float* beta  = (const float*)d_in[5];

    float* out_px = (float*)d_out;                                  // (B,NPOINT,128)
    float* out_nx = out_px + (size_t)Bc * NPOINTc * COUTc;          // (B,NPOINT,3)

    char* w = (char*)d_ws;
    int*   cent = (int*)w;    w += (size_t)Bc * NPOINTc * 4;
    float* sn   = (float*)w;  w += (size_t)Bc * Nc * 4;
    int*   knn  = (int*)w;    w += (size_t)Bc * NPOINTc * NSAMPLEc * 4;
    float* bsum = (float*)w;  w += (size_t)NBUCK * COUTc * 4;
    float* bsq  = (float*)w;  w += (size_t)NBUCK * COUTc * 4;
    float* scsh = (float*)w;  w += 2 * COUTc * 4;

    hipMemsetAsync(bsum, 0, (size_t)NBUCK * COUTc * 4 * 2, stream);

    sq_norm_kernel<<<(Bc * Nc + 255) / 256, 256, 0, stream>>>(xyz, sn);
    fps_kernel<<<Bc, 512, 0, stream>>>(xyz, cent, out_nx);
    knn_kernel<<<Bc * NPOINTc, 256, 0, stream>>>(xyz, sn, cent, knn);
    gemm_stats_kernel<<<Bc * NPOINTc, 128, 0, stream>>>(px, xyz, out_nx, knn, W, bias, bsum, bsq);
    stats_finalize_kernel<<<1, 128, 0, stream>>>(bsum, bsq, gamma, beta, scsh);
    gemm_out_kernel<<<Bc * NPOINTc, 128, 0, stream>>>(px, xyz, out_nx, knn, W, bias, scsh, out_px);
}

// Round 7
// 3738.581 us; speedup vs baseline: 1.0988x; 1.0988x over previous
//
#include <hip/hip_runtime.h>
#include <math.h>

#define Bc 4
#define Nc 8192
#define NPOINTc 2048
#define NSAMPLEc 16
#define CINc 64
#define COUTc 128
#define FDIMc 67
#define NBUCK 128
#define EPSc 1e-5f

// ---------------------------------------------------------------- K0: |xyz|^2 (f32, rn-chain)
__global__ void sq_norm_kernel(const float* __restrict__ xyz, float* __restrict__ sn) {
    int i = blockIdx.x * blockDim.x + threadIdx.x;
    if (i < Bc * Nc) {
        float x = xyz[i * 3], y = xyz[i * 3 + 1], z = xyz[i * 3 + 2];
        sn[i] = __fadd_rn(__fadd_rn(__fmul_rn(x, x), __fmul_rn(y, y)), __fmul_rn(z, z));
    }
}

// ---------------------------------------------------------------- K1: FPS — single barrier/iter
// One block/batch, 512 threads, 16 pts/thread. Every thread performs the final
// 8-partial reduce itself (no thread-0 serialization, no winner broadcast
// round-trip). Parity double-buffer pd/pi[2][8] makes ONE barrier per
// iteration safe: slot (it&1) is rewritten only at it+2, and every wave's
// read of slot(it) happens before barrier(it+1) which precedes any write(it+2).
// Distance math: exact f32 rn-chain, no FMA (reference semantics). Tie -> lowest idx.
__global__ __launch_bounds__(512) void fps_kernel(const float* __restrict__ xyz,
                                                  int* __restrict__ cent,
                                                  float* __restrict__ newxyz) {
    const int b = blockIdx.x;
    const float* base = xyz + (size_t)b * Nc * 3;
    const int t = threadIdx.x;
    const int lane = t & 63, wid = t >> 6;   // 8 waves

    __shared__ float P[Nc * 3];              // 96 KB point cache
    __shared__ float pd[2][8];
    __shared__ int   pi[2][8];

    for (int e = t; e < Nc * 3; e += 512) P[e] = base[e];

    float X[16], Y[16], Z[16], D[16];
#pragma unroll
    for (int k = 0; k < 16; ++k) {
        const int n = t + (k << 9);
        X[k] = base[n * 3 + 0];
        Y[k] = base[n * 3 + 1];
        Z[k] = base[n * 3 + 2];
        D[k] = 1e10f;
    }
    if (t == 0) {
        cent[b * NPOINTc] = 0;
        float* o = newxyz + (size_t)b * NPOINTc * 3;
        o[0] = base[0]; o[1] = base[1]; o[2] = base[2];
    }
    __syncthreads();

    float cx = P[0], cy = P[1], cz = P[2];

    for (int it = 1; it < NPOINTc; ++it) {
        float bd = -1.0f; int bi = 0;
#pragma unroll
        for (int k = 0; k < 16; ++k) {
            const float dx = __fsub_rn(X[k], cx);
            const float dy = __fsub_rn(Y[k], cy);
            const float dz = __fsub_rn(Z[k], cz);
            const float d2 = __fadd_rn(__fadd_rn(__fmul_rn(dx, dx), __fmul_rn(dy, dy)),
                                       __fmul_rn(dz, dz));
            if (d2 < D[k]) D[k] = d2;        // minimum(distance, dist)
            // n = t + k*512 ascends with k: strict > keeps lowest index on tie
            if (D[k] > bd) { bd = D[k]; bi = t + (k << 9); }
        }
        // intra-wave butterfly lex-argmax (tie -> lowest global index)
#pragma unroll
        for (int off = 32; off > 0; off >>= 1) {
            const float od = __shfl_xor(bd, off, 64);
            const int   oi = __shfl_xor(bi, off, 64);
            if (od > bd || (od == bd && oi < bi)) { bd = od; bi = oi; }
        }
        const int par = it & 1;
        if (lane == 0) { pd[par][wid] = bd; pi[par][wid] = bi; }
        __syncthreads();                     // the ONLY barrier per iteration

        // every thread reduces the 8 wave-partials identically (broadcast reads)
        float rdv = pd[par][0]; int riv = pi[par][0];
#pragma unroll
        for (int j = 1; j < 8; ++j) {
            const float d = pd[par][j]; const int i2 = pi[par][j];
            if (d > rdv || (d == rdv && i2 < riv)) { rdv = d; riv = i2; }
        }
        cx = P[riv * 3 + 0]; cy = P[riv * 3 + 1]; cz = P[riv * 3 + 2];

        if (t == 0) {                        // off the critical path (fire & forget)
            cent[b * NPOINTc + it] = riv;
            float* o = newxyz + ((size_t)b * NPOINTc + it) * 3;
            o[0] = cx; o[1] = cy; o[2] = cz;
        }
    }
}

// ---------------------------------------------------------------- K2: KNN — wave-resident top-16
// One wave per (b,m), zero barriers. Per-lane sorted top-16 insertion in
// registers, then 16-round lex-min merge (per-lane LDS head pointer).
// Distance: square_distance semantics ((-2*dot)+s1)+s2, dot = BLAS FMA chain.
__global__ __launch_bounds__(64) void knn_kernel(const float* __restrict__ xyz,
                                                 const float* __restrict__ sn,
                                                 const int* __restrict__ cent,
                                                 int* __restrict__ knn) {
    const int g = blockIdx.x;                // b*NPOINT + m
    const int b = g >> 11;
    const int lane = threadIdx.x;
    const float* base = xyz + (size_t)b * Nc * 3;
    const float* snb = sn + (size_t)b * Nc;

    const int cm = cent[g];
    const float mx = base[cm * 3 + 0];
    const float my = base[cm * 3 + 1];
    const float mz = base[cm * 3 + 2];
    const float s1 = snb[cm];

    float dls[16];
    int   ils[16];
#pragma unroll
    for (int j = 0; j < 16; ++j) { dls[j] = INFINITY; ils[j] = -1; }

    for (int jj = 0; jj < Nc / 64; ++jj) {
        const int n = lane + (jj << 6);
        const float x = base[n * 3 + 0];
        const float y = base[n * 3 + 1];
        const float z = base[n * 3 + 2];
        const float dot = fmaf(z, mz, fmaf(y, my, __fmul_rn(x, mx)));
        float d = __fadd_rn(__fadd_rn(__fmul_rn(-2.0f, dot), s1), snb[n]);
        d = fmaxf(d, 0.0f);
        if (d < dls[15]) {                   // strict: equal dist keeps existing lower idx
            float cd = d; int ci = n;
#pragma unroll
            for (int j = 0; j < 16; ++j) {
                const bool less = cd < dls[j];
                const float td = less ? dls[j] : cd;
                const int   ti = less ? ils[j] : ci;
                dls[j] = less ? cd : dls[j];
                ils[j] = less ? ci : ils[j];
                cd = td; ci = ti;
            }
        }
    }

    __shared__ float ld[64][16];
    __shared__ int   li[64][16];
#pragma unroll
    for (int j = 0; j < 16; ++j) { ld[lane][j] = dls[j]; li[lane][j] = ils[j]; }

    int ptr = 0;
    int* out = knn + (size_t)g * NSAMPLEc;
    for (int r = 0; r < NSAMPLEc; ++r) {
        const float hd = ld[lane][ptr];      // own row only: no cross-lane dependency
        const int   hi = li[lane][ptr];
        float vd = hd; int vi = hi;
#pragma unroll
        for (int off = 32; off > 0; off >>= 1) {
            const float od = __shfl_xor(vd, off, 64);
            const int   oi = __shfl_xor(vi, off, 64);
            if (od < vd || (od == vd && oi < vi)) { vd = od; vi = oi; }
        }
        if (hd == vd && hi == vi) ptr++;     // unique winner (indices distinct) advances
        if (lane == r) out[r] = vi;
    }
}

// ---------------------------------------------------------------- staging helper (featT layout)
// featT[i][s]: transposed so the compute loop reads 16 rows as 4 aligned float4
// broadcasts per i. Row stride 20 floats (80 B): 16B-aligned rows, banks spread.
__device__ __forceinline__ void stage_featT(
        const float* __restrict__ px, const float* __restrict__ xyz,
        const float* __restrict__ newxyz, const int* __restrict__ knn,
        int g, int b, int t, float (*featT)[20], int* nidx, float* ctr) {
    if (t < 16) nidx[t] = knn[(size_t)g * NSAMPLEc + t];
    if (t < 3)  ctr[t] = newxyz[(size_t)g * 3 + t];
    __syncthreads();
    for (int e = t; e < 16 * FDIMc; e += 128) {
        const int s = e / FDIMc, i = e % FDIMc;
        float v;
        if (i < CINc) v = px[((size_t)b * Nc + nidx[s]) * CINc + i];
        else          v = __fsub_rn(xyz[((size_t)b * Nc + nidx[s]) * 3 + (i - CINc)], ctr[i - CINc]);
        featT[i][s] = v;
    }
    __syncthreads();
}

// ---------------------------------------------------------------- K3: GEMM + BN stats
// 128 threads = 128 channels; i-outer with acc[16]: W streamed ONCE per block
// (67 scalar loads/thread), feat as 4 broadcast float4 per i.
__global__ __launch_bounds__(128) void gemm_stats_kernel(
        const float* __restrict__ px, const float* __restrict__ xyz,
        const float* __restrict__ newxyz, const int* __restrict__ knn,
        const float* __restrict__ W, const float* __restrict__ bias,
        float* __restrict__ bsum, float* __restrict__ bsq) {
    const int g = blockIdx.x;
    const int b = g >> 11;
    const int t = threadIdx.x;

    __shared__ __align__(16) float featT[FDIMc][20];
    __shared__ int nidx[16];
    __shared__ float ctr[3];
    stage_featT(px, xyz, newxyz, knn, g, b, t, featT, nidx, ctr);

    float acc[16];
    const float bc = bias[t];
#pragma unroll
    for (int r = 0; r < 16; ++r) acc[r] = bc;

    for (int i = 0; i < FDIMc; ++i) {
        const float w = W[i * COUTc + t];
        const float4* fr = (const float4*)featT[i];
        const float4 f0 = fr[0], f1 = fr[1], f2 = fr[2], f3 = fr[3];
        acc[0]  = fmaf(f0.x, w, acc[0]);  acc[1]  = fmaf(f0.y, w, acc[1]);
        acc[2]  = fmaf(f0.z, w, acc[2]);  acc[3]  = fmaf(f0.w, w, acc[3]);
        acc[4]  = fmaf(f1.x, w, acc[4]);  acc[5]  = fmaf(f1.y, w, acc[5]);
        acc[6]  = fmaf(f1.z, w, acc[6]);  acc[7]  = fmaf(f1.w, w, acc[7]);
        acc[8]  = fmaf(f2.x, w, acc[8]);  acc[9]  = fmaf(f2.y, w, acc[9]);
        acc[10] = fmaf(f2.z, w, acc[10]); acc[11] = fmaf(f2.w, w, acc[11]);
        acc[12] = fmaf(f3.x, w, acc[12]); acc[13] = fmaf(f3.y, w, acc[13]);
        acc[14] = fmaf(f3.z, w, acc[14]); acc[15] = fmaf(f3.w, w, acc[15]);
    }
    float s = 0.f, q = 0.f;
#pragma unroll
    for (int r = 0; r < 16; ++r) { s += acc[r]; q += acc[r] * acc[r]; }
    atomicAdd(&bsum[(g & (NBUCK - 1)) * COUTc + t], s);
    atomicAdd(&bsq [(g & (NBUCK - 1)) * COUTc + t], q);
}

// ---------------------------------------------------------------- K4: finalize stats
__global__ void stats_finalize_kernel(const float* __restrict__ bsum,
                                      const float* __restrict__ bsq,
                                      const float* __restrict__ gamma,
                                      const float* __restrict__ beta,
                                      float* __restrict__ scsh) {
    const int c = threadIdx.x;  // 128
    float S = 0.f, Q = 0.f;
    for (int k = 0; k < NBUCK; ++k) { S += bsum[k * COUTc + c]; Q += bsq[k * COUTc + c]; }
    const float cnt = (float)(Bc * NPOINTc * NSAMPLEc);
    const float mu = S / cnt;
    const float var = Q / cnt - mu * mu;
    const float sc = gamma[c] / sqrtf(var + EPSc);
    scsh[c] = sc;
    scsh[COUTc + c] = beta[c] - mu * sc;
}

// ---------------------------------------------------------------- K5: GEMM + BN + ReLU + maxpool
__global__ __launch_bounds__(128) void gemm_out_kernel(
        const float* __restrict__ px, const float* __restrict__ xyz,
        const float* __restrict__ newxyz, const int* __restrict__ knn,
        const float* __restrict__ W, const float* __restrict__ bias,
        const float* __restrict__ scsh, float* __restrict__ out) {
    const int g = blockIdx.x;
    const int b = g >> 11;
    const int t = threadIdx.x;

    __shared__ __align__(16) float featT[FDIMc][20];
    __shared__ int nidx[16];
    __shared__ float ctr[3];
    stage_featT(px, xyz, newxyz, knn, g, b, t, featT, nidx, ctr);

    float acc[16];
    const float bc = bias[t];
#pragma unroll
    for (int r = 0; r < 16; ++r) acc[r] = bc;

    for (int i = 0; i < FDIMc; ++i) {
        const float w = W[i * COUTc + t];
        const float4* fr = (const float4*)featT[i];
        const float4 f0 = fr[0], f1 = fr[1], f2 = fr[2], f3 = fr[3];
        acc[0]  = fmaf(f0.x, w, acc[0]);  acc[1]  = fmaf(f0.y, w, acc[1]);
        acc[2]  = fmaf(f0.z, w, acc[2]);  acc[3]  = fmaf(f0.w, w, acc[3]);
        acc[4]  = fmaf(f1.x, w, acc[4]);  acc[5]  = fmaf(f1.y, w, acc[5]);
        acc[6]  = fmaf(f1.z, w, acc[6]);  acc[7]  = fmaf(f1.w, w, acc[7]);
        acc[8]  = fmaf(f2.x, w, acc[8]);  acc[9]  = fmaf(f2.y, w, acc[9]);
        acc[10] = fmaf(f2.z, w, acc[10]); acc[11] = fmaf(f2.w, w, acc[11]);
        acc[12] = fmaf(f3.x, w, acc[12]); acc[13] = fmaf(f3.y, w, acc[13]);
        acc[14] = fmaf(f3.z, w, acc[14]); acc[15] = fmaf(f3.w, w, acc[15]);
    }

    const float sc = scsh[t], sh = scsh[COUTc + t];
    float m = -INFINITY;
#pragma unroll
    for (int r = 0; r < 16; ++r) {
        const float v = fmaxf(fmaf(acc[r], sc, sh), 0.0f);   // BN + ReLU
        m = fmaxf(m, v);
    }
    out[(size_t)g * COUTc + t] = m;
}

// ---------------------------------------------------------------- launch
extern "C" void kernel_launch(void* const* d_in, const int* in_sizes, int n_in,
                              void* d_out, int out_size, void* d_ws, size_t ws_size,
                              hipStream_t stream) {
    const float* px    = (const float*)d_in[0];
    const float* xyz   = (const float*)d_in[1];
    const float* W     = (const float*)d_in[2];
    const float* bias  = (const float*)d_in[3];
    const float* gamma = (const float*)d_in[4];
    const float* beta  = (const float*)d_in[5];

    float* out_px = (float*)d_out;                                  // (B,NPOINT,128)
    float* out_nx = out_px + (size_t)Bc * NPOINTc * COUTc;          // (B,NPOINT,3)

    char* w = (char*)d_ws;
    int*   cent = (int*)w;    w += (size_t)Bc * NPOINTc * 4;
    float* sn   = (float*)w;  w += (size_t)Bc * Nc * 4;
    int*   knn  = (int*)w;    w += (size_t)Bc * NPOINTc * NSAMPLEc * 4;
    float* bsum = (float*)w;  w += (size_t)NBUCK * COUTc * 4;
    float* bsq  = (float*)w;  w += (size_t)NBUCK * COUTc * 4;
    float* scsh = (float*)w;  w += 2 * COUTc * 4;

    hipMemsetAsync(bsum, 0, (size_t)NBUCK * COUTc * 4 * 2, stream);

    sq_norm_kernel<<<(Bc * Nc + 255) / 256, 256, 0, stream>>>(xyz, sn);
    fps_kernel<<<Bc, 512, 0, stream>>>(xyz, cent, out_nx);
    knn_kernel<<<Bc * NPOINTc, 64, 0, stream>>>(xyz, sn, cent, knn);
    gemm_stats_kernel<<<Bc * NPOINTc, 128, 0, stream>>>(px, xyz, out_nx, knn, W, bias, bsum, bsq);
    stats_finalize_kernel<<<1, 128, 0, stream>>>(bsum, bsq, gamma, beta, scsh);
    gemm_out_kernel<<<Bc * NPOINTc, 128, 0, stream>>>(px, xyz, out_nx, knn, W, bias, scsh, out_px);
}

// Round 8
// 3287.782 us; speedup vs baseline: 1.2495x; 1.1371x over previous
//
#include <hip/hip_runtime.h>
#include <math.h>

#define Bc 4
#define Nc 8192
#define NPOINTc 2048
#define NSAMPLEc 16
#define CINc 64
#define COUTc 128
#define FDIMc 67
#define NBUCK 128
#define EPSc 1e-5f

// ---------------------------------------------------------------- K0: |xyz|^2 (f32, rn-chain)
__global__ void sq_norm_kernel(const float* __restrict__ xyz, float* __restrict__ sn) {
    int i = blockIdx.x * blockDim.x + threadIdx.x;
    if (i < Bc * Nc) {
        float x = xyz[i * 3], y = xyz[i * 3 + 1], z = xyz[i * 3 + 2];
        sn[i] = __fadd_rn(__fadd_rn(__fmul_rn(x, x), __fmul_rn(y, y)), __fmul_rn(z, z));
    }
}

// ---------------------------------------------------------------- DPP lex-argmax step
// VALU-pipe cross-lane (v_mov_b32_dpp), ~4cy forwarding vs ~100cy LDS-pipe shuffles.
// Invalid-source lanes (row boundary, bound_ctrl=false) keep old = own value ->
// self-compare is a no-op (correct identity). Strict > keeps lowest index on tie.
template <int CTRL>
__device__ __forceinline__ void amax_dpp(float& bd, int& bi) {
    const int od_i = __builtin_amdgcn_update_dpp(__float_as_int(bd), __float_as_int(bd),
                                                 CTRL, 0xF, 0xF, false);
    const int oi   = __builtin_amdgcn_update_dpp(bi, bi, CTRL, 0xF, 0xF, false);
    const float od = __int_as_float(od_i);
    if (od > bd || (od == bd && oi < bi)) { bd = od; bi = oi; }
}

// ---------------------------------------------------------------- K1: FPS — DPP reduction
// One block/batch, 512 threads (8 waves), 16 pts/thread.
// Per iteration: rn-chain distance update (exact reference semantics) ->
// per-thread 4-level tree argmax -> wave64 DPP argmax (shr1/2/4/8 + bcast15/31,
// result in lane 63) -> one barrier -> lanes 0-7 read 8 partials -> 3-step DPP
// argmax -> readlane(7) -> winner coords from LDS point cache.
// Parity double-buffered partial slots make the single barrier race-free.
__global__ __launch_bounds__(512) void fps_kernel(const float* __restrict__ xyz,
                                                  int* __restrict__ cent,
                                                  float* __restrict__ newxyz) {
    const int b = blockIdx.x;
    const float* base = xyz + (size_t)b * Nc * 3;
    const int t = threadIdx.x;
    const int lane = t & 63, wid = t >> 6;   // 8 waves

    __shared__ float P[Nc * 3];              // 96 KB point cache
    __shared__ float pd[2][8];
    __shared__ int   pi[2][8];

    for (int e = t; e < Nc * 3; e += 512) P[e] = base[e];

    float X[16], Y[16], Z[16], D[16];
#pragma unroll
    for (int k = 0; k < 16; ++k) {
        const int n = t + (k << 9);
        X[k] = base[n * 3 + 0];
        Y[k] = base[n * 3 + 1];
        Z[k] = base[n * 3 + 2];
        D[k] = 1e10f;
    }
    if (t == 0) {
        cent[b * NPOINTc] = 0;
        float* o = newxyz + (size_t)b * NPOINTc * 3;
        o[0] = base[0]; o[1] = base[1]; o[2] = base[2];
    }
    __syncthreads();

    float cx = P[0], cy = P[1], cz = P[2];

    for (int it = 1; it < NPOINTc; ++it) {
        // --- distance update: exact f32 rn-chain, no FMA (reference semantics)
#pragma unroll
        for (int k = 0; k < 16; ++k) {
            const float dx = __fsub_rn(X[k], cx);
            const float dy = __fsub_rn(Y[k], cy);
            const float dz = __fsub_rn(Z[k], cz);
            const float d2 = __fadd_rn(__fadd_rn(__fmul_rn(dx, dx), __fmul_rn(dy, dy)),
                                       __fmul_rn(dz, dz));
            if (d2 < D[k]) D[k] = d2;        // minimum(distance, dist)
        }
        // --- per-thread tree argmax over 16 (left operand always lower index:
        //     strict > on the right operand preserves lowest-index tie-break)
        float a0[8]; int x0[8];
#pragma unroll
        for (int k = 0; k < 8; ++k) {
            const bool g = D[2 * k + 1] > D[2 * k];
            a0[k] = g ? D[2 * k + 1] : D[2 * k];
            x0[k] = t + ((g ? (2 * k + 1) : (2 * k)) << 9);
        }
        float a1[4]; int x1[4];
#pragma unroll
        for (int k = 0; k < 4; ++k) {
            const bool g = a0[2 * k + 1] > a0[2 * k];
            a1[k] = g ? a0[2 * k + 1] : a0[2 * k];
            x1[k] = g ? x0[2 * k + 1] : x0[2 * k];
        }
        float a2[2]; int x2[2];
#pragma unroll
        for (int k = 0; k < 2; ++k) {
            const bool g = a1[2 * k + 1] > a1[2 * k];
            a2[k] = g ? a1[2 * k + 1] : a1[2 * k];
            x2[k] = g ? x1[2 * k + 1] : x1[2 * k];
        }
        float bd = (a2[1] > a2[0]) ? a2[1] : a2[0];
        int   bi = (a2[1] > a2[0]) ? x2[1] : x2[0];

        // --- wave64 DPP lex-argmax; result lands in lane 63
        amax_dpp<0x111>(bd, bi);             // row_shr:1
        amax_dpp<0x112>(bd, bi);             // row_shr:2
        amax_dpp<0x114>(bd, bi);             // row_shr:4
        amax_dpp<0x118>(bd, bi);             // row_shr:8
        amax_dpp<0x142>(bd, bi);             // row_bcast:15
        amax_dpp<0x143>(bd, bi);             // row_bcast:31

        const int par = it & 1;
        if (lane == 63) { pd[par][wid] = bd; pi[par][wid] = bi; }
        __syncthreads();                     // the only barrier per iteration

        // --- cross-wave: lanes 0-7 load partials, 3-step DPP argmax -> lane 7
        float d8 = (lane < 8) ? pd[par][lane] : -INFINITY;
        int   i8 = (lane < 8) ? pi[par][lane] : 0x7fffffff;
        amax_dpp<0x111>(d8, i8);
        amax_dpp<0x112>(d8, i8);
        amax_dpp<0x114>(d8, i8);
        const int riv = __builtin_amdgcn_readlane(i8, 7);   // uniform winner index

        cx = P[riv * 3 + 0]; cy = P[riv * 3 + 1]; cz = P[riv * 3 + 2];

        if (t == 0) {                        // off the critical path
            cent[b * NPOINTc + it] = riv;
            float* o = newxyz + ((size_t)b * NPOINTc + it) * 3;
            o[0] = cx; o[1] = cy; o[2] = cz;
        }
    }
}

// ---------------------------------------------------------------- K2: KNN — wave-resident top-16
// One wave per (b,m), zero barriers. Per-lane sorted top-16 insertion in
// registers, then 16-round lex-min merge (per-lane LDS head pointer).
// Distance: square_distance semantics ((-2*dot)+s1)+s2, dot = BLAS FMA chain.
__global__ __launch_bounds__(64) void knn_kernel(const float* __restrict__ xyz,
                                                 const float* __restrict__ sn,
                                                 const int* __restrict__ cent,
                                                 int* __restrict__ knn) {
    const int g = blockIdx.x;                // b*NPOINT + m
    const int b = g >> 11;
    const int lane = threadIdx.x;
    const float* base = xyz + (size_t)b * Nc * 3;
    const float* snb = sn + (size_t)b * Nc;

    const int cm = cent[g];
    const float mx = base[cm * 3 + 0];
    const float my = base[cm * 3 + 1];
    const float mz = base[cm * 3 + 2];
    const float s1 = snb[cm];

    float dls[16];
    int   ils[16];
#pragma unroll
    for (int j = 0; j < 16; ++j) { dls[j] = INFINITY; ils[j] = -1; }

    for (int jj = 0; jj < Nc / 64; ++jj) {
        const int n = lane + (jj << 6);
        const float x = base[n * 3 + 0];
        const float y = base[n * 3 + 1];
        const float z = base[n * 3 + 2];
        const float dot = fmaf(z, mz, fmaf(y, my, __fmul_rn(x, mx)));
        float d = __fadd_rn(__fadd_rn(__fmul_rn(-2.0f, dot), s1), snb[n]);
        d = fmaxf(d, 0.0f);
        if (d < dls[15]) {                   // strict: equal dist keeps existing lower idx
            float cd = d; int ci = n;
#pragma unroll
            for (int j = 0; j < 16; ++j) {
                const bool less = cd < dls[j];
                const float td = less ? dls[j] : cd;
                const int   ti = less ? ils[j] : ci;
                dls[j] = less ? cd : dls[j];
                ils[j] = less ? ci : ils[j];
                cd = td; ci = ti;
            }
        }
    }

    __shared__ float ld[64][16];
    __shared__ int   li[64][16];
#pragma unroll
    for (int j = 0; j < 16; ++j) { ld[lane][j] = dls[j]; li[lane][j] = ils[j]; }

    int ptr = 0;
    int* out = knn + (size_t)g * NSAMPLEc;
    for (int r = 0; r < NSAMPLEc; ++r) {
        const float hd = ld[lane][ptr];      // own row only: no cross-lane dependency
        const int   hi = li[lane][ptr];
        float vd = hd; int vi = hi;
#pragma unroll
        for (int off = 32; off > 0; off >>= 1) {
            const float od = __shfl_xor(vd, off, 64);
            const int   oi = __shfl_xor(vi, off, 64);
            if (od < vd || (od == vd && oi < vi)) { vd = od; vi = oi; }
        }
        if (hd == vd && hi == vi) ptr++;     // unique winner (indices distinct) advances
        if (lane == r) out[r] = vi;
    }
}

// ---------------------------------------------------------------- staging helper (featT layout)
__device__ __forceinline__ void stage_featT(
        const float* __restrict__ px, const float* __restrict__ xyz,
        const float* __restrict__ newxyz, const int* __restrict__ knn,
        int g, int b, int t, float (*featT)[20], int* nidx, float* ctr) {
    if (t < 16) nidx[t] = knn[(size_t)g * NSAMPLEc + t];
    if (t < 3)  ctr[t] = newxyz[(size_t)g * 3 + t];
    __syncthreads();
    for (int e = t; e < 16 * FDIMc; e += 128) {
        const int s = e / FDIMc, i = e % FDIMc;
        float v;
        if (i < CINc) v = px[((size_t)b * Nc + nidx[s]) * CINc + i];
        else          v = __fsub_rn(xyz[((size_t)b * Nc + nidx[s]) * 3 + (i - CINc)], ctr[i - CINc]);
        featT[i][s] = v;
    }
    __syncthreads();
}

// ---------------------------------------------------------------- K3: GEMM + BN stats
__global__ __launch_bounds__(128) void gemm_stats_kernel(
        const float* __restrict__ px, const float* __restrict__ xyz,
        const float* __restrict__ newxyz, const int* __restrict__ knn,
        const float* __restrict__ W, const float* __restrict__ bias,
        float* __restrict__ bsum, float* __restrict__ bsq) {
    const int g = blockIdx.x;
    const int b = g >> 11;
    const int t = threadIdx.x;

    __shared__ __align__(16) float featT[FDIMc][20];
    __shared__ int nidx[16];
    __shared__ float ctr[3];
    stage_featT(px, xyz, newxyz, knn, g, b, t, featT, nidx, ctr);

    float acc[16];
    const float bc = bias[t];
#pragma unroll
    for (int r = 0; r < 16; ++r) acc[r] = bc;

    for (int i = 0; i < FDIMc; ++i) {
        const float w = W[i * COUTc + t];
        const float4* fr = (const float4*)featT[i];
        const float4 f0 = fr[0], f1 = fr[1], f2 = fr[2], f3 = fr[3];
        acc[0]  = fmaf(f0.x, w, acc[0]);  acc[1]  = fmaf(f0.y, w, acc[1]);
        acc[2]  = fmaf(f0.z, w, acc[2]);  acc[3]  = fmaf(f0.w, w, acc[3]);
        acc[4]  = fmaf(f1.x, w, acc[4]);  acc[5]  = fmaf(f1.y, w, acc[5]);
        acc[6]  = fmaf(f1.z, w, acc[6]);  acc[7]  = fmaf(f1.w, w, acc[7]);
        acc[8]  = fmaf(f2.x, w, acc[8]);  acc[9]  = fmaf(f2.y, w, acc[9]);
        acc[10] = fmaf(f2.z, w, acc[10]); acc[11] = fmaf(f2.w, w, acc[11]);
        acc[12] = fmaf(f3.x, w, acc[12]); acc[13] = fmaf(f3.y, w, acc[13]);
        acc[14] = fmaf(f3.z, w, acc[14]); acc[15] = fmaf(f3.w, w, acc[15]);
    }
    float s = 0.f, q = 0.f;
#pragma unroll
    for (int r = 0; r < 16; ++r) { s += acc[r]; q += acc[r] * acc[r]; }
    atomicAdd(&bsum[(g & (NBUCK - 1)) * COUTc + t], s);
    atomicAdd(&bsq [(g & (NBUCK - 1)) * COUTc + t], q);
}

// ---------------------------------------------------------------- K4: finalize stats
__global__ void stats_finalize_kernel(const float* __restrict__ bsum,
                                      const float* __restrict__ bsq,
                                      const float* __restrict__ gamma,
                                      const float* __restrict__ beta,
                                      float* __restrict__ scsh) {
    const int c = threadIdx.x;  // 128
    float S = 0.f, Q = 0.f;
    for (int k = 0; k < NBUCK; ++k) { S += bsum[k * COUTc + c]; Q += bsq[k * COUTc + c]; }
    const float cnt = (float)(Bc * NPOINTc * NSAMPLEc);
    const float mu = S / cnt;
    const float var = Q / cnt - mu * mu;
    const float sc = gamma[c] / sqrtf(var + EPSc);
    scsh[c] = sc;
    scsh[COUTc + c] = beta[c] - mu * sc;
}

// ---------------------------------------------------------------- K5: GEMM + BN + ReLU + maxpool
__global__ __launch_bounds__(128) void gemm_out_kernel(
        const float* __restrict__ px, const float* __restrict__ xyz,
        const float* __restrict__ newxyz, const int* __restrict__ knn,
        const float* __restrict__ W, const float* __restrict__ bias,
        const float* __restrict__ scsh, float* __restrict__ out) {
    const int g = blockIdx.x;
    const int b = g >> 11;
    const int t = threadIdx.x;

    __shared__ __align__(16) float featT[FDIMc][20];
    __shared__ int nidx[16];
    __shared__ float ctr[3];
    stage_featT(px, xyz, newxyz, knn, g, b, t, featT, nidx, ctr);

    float acc[16];
    const float bc = bias[t];
#pragma unroll
    for (int r = 0; r < 16; ++r) acc[r] = bc;

    for (int i = 0; i < FDIMc; ++i) {
        const float w = W[i * COUTc + t];
        const float4* fr = (const float4*)featT[i];
        const float4 f0 = fr[0], f1 = fr[1], f2 = fr[2], f3 = fr[3];
        acc[0]  = fmaf(f0.x, w, acc[0]);  acc[1]  = fmaf(f0.y, w, acc[1]);
        acc[2]  = fmaf(f0.z, w, acc[2]);  acc[3]  = fmaf(f0.w, w, acc[3]);
        acc[4]  = fmaf(f1.x, w, acc[4]);  acc[5]  = fmaf(f1.y, w, acc[5]);
        acc[6]  = fmaf(f1.z, w, acc[6]);  acc[7]  = fmaf(f1.w, w, acc[7]);
        acc[8]  = fmaf(f2.x, w, acc[8]);  acc[9]  = fmaf(f2.y, w, acc[9]);
        acc[10] = fmaf(f2.z, w, acc[10]); acc[11] = fmaf(f2.w, w, acc[11]);
        acc[12] = fmaf(f3.x, w, acc[12]); acc[13] = fmaf(f3.y, w, acc[13]);
        acc[14] = fmaf(f3.z, w, acc[14]); acc[15] = fmaf(f3.w, w, acc[15]);
    }

    const float sc = scsh[t], sh = scsh[COUTc + t];
    float m = -INFINITY;
#pragma unroll
    for (int r = 0; r < 16; ++r) {
        const float v = fmaxf(fmaf(acc[r], sc, sh), 0.0f);   // BN + ReLU
        m = fmaxf(m, v);
    }
    out[(size_t)g * COUTc + t] = m;
}

// ---------------------------------------------------------------- launch
extern "C" void kernel_launch(void* const* d_in, const int* in_sizes, int n_in,
                              void* d_out, int out_size, void* d_ws, size_t ws_size,
                              hipStream_t stream) {
    const float* px    = (const float*)d_in[0];
    const float* xyz   = (const float*)d_in[1];
    const float* W     = (const float*)d_in[2];
    const float* bias  = (const float*)d_in[3];
    const float* gamma = (const float*)d_in[4];
    const float* beta  = (const float*)d_in[5];

    float* out_px = (float*)d_out;                                  // (B,NPOINT,128)
    float* out_nx = out_px + (size_t)Bc * NPOINTc * COUTc;          // (B,NPOINT,3)

    char* w = (char*)d_ws;
    int*   cent = (int*)w;    w += (size_t)Bc * NPOINTc * 4;
    float* sn   = (float*)w;  w += (size_t)Bc * Nc * 4;
    int*   knn  = (int*)w;    w += (size_t)Bc * NPOINTc * NSAMPLEc * 4;
    float* bsum = (float*)w;  w += (size_t)NBUCK * COUTc * 4;
    float* bsq  = (float*)w;  w += (size_t)NBUCK * COUTc * 4;
    float* scsh = (float*)w;  w += 2 * COUTc * 4;

    hipMemsetAsync(bsum, 0, (size_t)NBUCK * COUTc * 4 * 2, stream);

    sq_norm_kernel<<<(Bc * Nc + 255) / 256, 256, 0, stream>>>(xyz, sn);
    fps_kernel<<<Bc, 512, 0, stream>>>(xyz, cent, out_nx);
    knn_kernel<<<Bc * NPOINTc, 64, 0, stream>>>(xyz, sn, cent, knn);
    gemm_stats_kernel<<<Bc * NPOINTc, 128, 0, stream>>>(px, xyz, out_nx, knn, W, bias, bsum, bsq);
    stats_finalize_kernel<<<1, 128, 0, stream>>>(bsum, bsq, gamma, beta, scsh);
    gemm_out_kernel<<<Bc * NPOINTc, 128, 0, stream>>>(px, xyz, out_nx, knn, W, bias, scsh, out_px);
}